// Round 11
// baseline (238.071 us; speedup 1.0000x reference)
//
#include <hip/hip_runtime.h>

#define N_NODES 100000
#define N_EDGES 1600000
#define IN_C 64
#define HID_C 64
#define OUT_C 32

#define NB 391              // ceil(100000/256) dst buckets of 256 nodes
#define BSHIFT 8
#define BMASK 255
#define SEG_CAP 4864        // per-bucket capacity: mean 4096 + align pad + slack
#define EPB 2048            // edges per bin block (halved: LDS -> 29KB, union -> 32KB)
#define BIN_BLOCKS ((N_EDGES + EPB - 1) / EPB)  // 782
#define G1_BLOCKS ((N_NODES + 63) / 64)         // 1563
#define SMASK 0x1FFFF       // 17-bit src field
#define FIXSCALE 34359738368.0f   // 2^35: count<<48 | sum(w)<<35 can't overflow

// bf16 pack/unpack (round-to-nearest-even)
__device__ __forceinline__ unsigned int bpack(float a, float b) {
    unsigned int ua = __float_as_uint(a);
    ua += 0x7FFFu + ((ua >> 16) & 1u);
    unsigned int ub = __float_as_uint(b);
    ub += 0x7FFFu + ((ub >> 16) & 1u);
    return (ua >> 16) | (ub & 0xFFFF0000u);
}
__device__ __forceinline__ float2 bup(unsigned int v) {
    return make_float2(__uint_as_float(v << 16), __uint_as_float(v & 0xFFFF0000u));
}

// ---------------- fused pass 1: bin (blocks 0..781) + gemm1 unscaled (rest) ----------------

struct BinSh {
    int2 recs[EPB];     // 16 KB
    int meta[EPB];      // 8 KB: b | copy<<9 | rank<<10
    int hist[2][NB];    // 3.1 KB, two copies to halve LDS-atomic collisions
    int gbase[NB];      // 1.6 KB
};
struct G1Sh {
    float XsT[64][64];  // 16 KB
    float Ws[64][64];   // 16 KB
};
union FusedSh { BinSh b; G1Sh g; };  // 32 KB -> 4-5 blocks/CU (was 51.5 KB -> 3)

__global__ void __launch_bounds__(256) fused1_kernel(
    const int* __restrict__ src, const int* __restrict__ dst,
    const float* __restrict__ w, int* __restrict__ gcnt, int2* __restrict__ seg,
    const float* __restrict__ X, const float* __restrict__ W,
    unsigned int* __restrict__ XWu) {
    __shared__ FusedSh sh;
    int tid = threadIdx.x;
    if (blockIdx.x < BIN_BLOCKS) {
        // ---- bin body ----
        for (int i = tid; i < 2 * NB; i += 256) sh.b.hist[0][i] = 0;
        __syncthreads();
        int e0 = blockIdx.x * EPB;
        int n = min(EPB, N_EDGES - e0);   // multiple of 4 (last block = 512)
        int cp = tid >> 7;                // waves 0-1 -> hist copy 0, waves 2-3 -> copy 1
        const int4* src4 = (const int4*)(src + e0);
        const int4* dst4 = (const int4*)(dst + e0);
        const float4* w4 = (const float4*)(w + e0);
        int n4 = n >> 2;
        // transposed slots: edge K of chunk i -> K*n4+i (stride-1 per lane, conflict-free)
        for (int i = tid; i < n4; i += 256) {
            int4 s = src4[i];
            int4 d = dst4[i];
            float4 ww = w4[i];
#define BIN_ONE(K, SS, DD, WW)                                             \
            {                                                              \
                int b = (DD) >> BSHIFT;                                    \
                int slot = K * n4 + i;                                     \
                sh.b.recs[slot] = make_int2((SS) | (((DD) & BMASK) << 17), \
                                            __float_as_int(WW));           \
                int rank = atomicAdd(&sh.b.hist[cp][b], 1);                \
                sh.b.meta[slot] = b | (cp << 9) | (rank << 10);            \
            }
            BIN_ONE(0, s.x, d.x, ww.x)
            BIN_ONE(1, s.y, d.y, ww.y)
            BIN_ONE(2, s.z, d.z, ww.z)
            BIN_ONE(3, s.w, d.w, ww.w)
#undef BIN_ONE
        }
        __syncthreads();
        for (int b = tid; b < NB; b += 256) {
            int c = sh.b.hist[0][b] + sh.b.hist[1][b];
            sh.b.gbase[b] = c ? atomicAdd(&gcnt[b], c) : 0;
        }
        __syncthreads();
        for (int i = tid; i < n; i += 256) {
            int m = sh.b.meta[i];
            int b = m & 511;
            int rank = (m >> 10) + ((m & 512) ? sh.b.hist[0][b] : 0);
            int pos = sh.b.gbase[b] + rank;
            if (pos < SEG_CAP) seg[(size_t)b * SEG_CAP + pos] = sh.b.recs[i];
        }
    } else {
        // ---- gemm1 body: XWu = bf16(X @ W1), unscaled ----
        {
            const float4* Wv = (const float4*)W;
            float4* Wsv = (float4*)&sh.g.Ws[0][0];
            for (int i = tid; i < 1024; i += 256) Wsv[i] = Wv[i];
        }
        int row0 = (blockIdx.x - BIN_BLOCKS) * 64;
        int rmax = N_NODES - row0;
        for (int i = tid; i < 64 * 16; i += 256) {
            int r = i & 63, kq = i >> 6;  // consecutive lanes -> consecutive rows (conflict-free)
            float4 v = (r < rmax) ? ((const float4*)(X + (size_t)(row0 + r) * IN_C))[kq]
                                  : make_float4(0.f, 0.f, 0.f, 0.f);
            sh.g.XsT[4 * kq + 0][r] = v.x;
            sh.g.XsT[4 * kq + 1][r] = v.y;
            sh.g.XsT[4 * kq + 2][r] = v.z;
            sh.g.XsT[4 * kq + 3][r] = v.w;
        }
        __syncthreads();
        int tr = tid >> 4, tc = tid & 15;
        float acc[4][4] = {};
        float a[4], bb[4];
#pragma unroll 8
        for (int k = 0; k < 64; ++k) {
            *(float4*)a = *(const float4*)&sh.g.XsT[k][4 * tr];
            *(float4*)bb = *(const float4*)&sh.g.Ws[k][4 * tc];
#pragma unroll
            for (int i = 0; i < 4; ++i)
#pragma unroll
                for (int j = 0; j < 4; ++j) acc[i][j] += a[i] * bb[j];
        }
#pragma unroll
        for (int i = 0; i < 4; ++i) {
            int rl = 4 * tr + i;
            if (rl < rmax) {
                int row = row0 + rl;
                uint2 o;
                o.x = bpack(acc[i][0], acc[i][1]);
                o.y = bpack(acc[i][2], acc[i][3]);
                ((uint2*)XWu)[(size_t)row * 16 + tc] = o;
            }
        }
    }
}

// ---------------- pass 2: per-bucket counting sort -> runs + dinv + XW scale ----------------

__global__ void __launch_bounds__(256) bsort_kernel(const int* __restrict__ gcnt,
                                                    const int2* __restrict__ seg,
                                                    int2* __restrict__ seg2,
                                                    float* __restrict__ dinv,
                                                    int2* __restrict__ rowRC,
                                                    unsigned int* __restrict__ XWs) {
    __shared__ int2 recs[SEG_CAP];               // 38 KB
    __shared__ unsigned long long packed[256];   // 2 KB
    __shared__ int meta[SEG_CAP];                // 19 KB
    __shared__ int sarr[256];
    __shared__ int ofs0[256];
    __shared__ float dinvsh[256];
    int tid = threadIdx.x, b = blockIdx.x;
    int n = min(gcnt[b], SEG_CAP);
    const int2* sp = seg + (size_t)b * SEG_CAP;
    packed[tid] = 0ULL;
    __syncthreads();
    for (int i = tid; i < n; i += 256) {
        int2 r = sp[i];
        recs[i] = r;
        int dl = (r.x >> 17) & BMASK;
        unsigned long long fixw =
            (unsigned long long)(__int_as_float(r.y) * FIXSCALE);
        unsigned long long old = atomicAdd(&packed[dl], (1ULL << 48) | fixw);
        meta[i] = dl | ((int)(old >> 48) << 8);
    }
    __syncthreads();
    unsigned long long p = packed[tid];
    int myc = (int)(p >> 48);
    float degw = (float)((double)(p & ((1ULL << 48) - 1)) * (1.0 / (double)FIXSCALE));
    float dv = rsqrtf(1.0f + degw);  // self-loop w=1
    dinvsh[tid] = dv;
    int node = (b << BSHIFT) + tid;
    if (node < N_NODES) dinv[node] = dv;
    int padc = (myc + 1) & ~1;  // even-align runs for int4 loads
    sarr[tid] = padc;
    __syncthreads();
    for (int off = 1; off < 256; off <<= 1) {
        int tmp = (tid >= off) ? sarr[tid - off] : 0;
        __syncthreads();
        sarr[tid] += tmp;
        __syncthreads();
    }
    int excl = sarr[tid] - padc;
    if (node < N_NODES) rowRC[node] = make_int2(b * SEG_CAP + excl, myc);
    ofs0[tid] = excl;
    __syncthreads();
    int2* op = seg2 + (size_t)b * SEG_CAP;
    for (int i = tid; i < n; i += 256) {
        int m = meta[i];
        int dl = m & BMASK, rank = m >> 8;
        op[ofs0[dl] + rank] = recs[i];
    }
    // ---- scale tail: XWs[row] *= dinv[row] (bf16 in place), coalesced uint4 ----
    int baseRow = b << BSHIFT;
    int rowsHere = min(256, N_NODES - baseRow);
    uint4* XW4 = (uint4*)XWs;
    for (int i = tid; i < rowsHere * 8; i += 256) {
        int nl = i >> 3;
        float s = dinvsh[nl];
        uint4 v = XW4[(size_t)(baseRow + nl) * 8 + (i & 7)];
        float2 f;
        f = bup(v.x); v.x = bpack(f.x * s, f.y * s);
        f = bup(v.y); v.y = bpack(f.x * s, f.y * s);
        f = bup(v.z); v.z = bpack(f.x * s, f.y * s);
        f = bup(v.w); v.w = bpack(f.x * s, f.y * s);
        XW4[(size_t)(baseRow + nl) * 8 + (i & 7)] = v;
    }
}

// ---------------- agg layer 1: 4 nodes/wave, 4 ch/lane (uint2), ReLU, bf16 out ----------

__global__ void __launch_bounds__(256) agg1_kernel(const int2* __restrict__ rowRC,
                                                   const int2* __restrict__ seg2,
                                                   const unsigned int* __restrict__ XWs,
                                                   const float* __restrict__ dinv,
                                                   const float* __restrict__ b1,
                                                   unsigned int* __restrict__ Hb) {
    int l16 = threadIdx.x & 15;
    int d = blockIdx.x * 16 + (threadIdx.x >> 4);
    if (d >= N_NODES) return;
    const uint2* XW2 = (const uint2*)XWs;   // row = 16 uint2
    float did = dinv[d];
    float4 bv = ((const float4*)b1)[l16];
    uint2 sv = XW2[(size_t)d * 16 + l16];
    float2 f0 = bup(sv.x), f1 = bup(sv.y);
    float a0 = bv.x + did * f0.x, a1 = bv.y + did * f0.y;
    float a2 = bv.z + did * f1.x, a3 = bv.w + did * f1.y;
    int2 rc = rowRC[d];
    int nc = rc.y;
    const int2* sp = seg2 + rc.x;
    const int4* sp4 = (const int4*)sp;
    int e = 0;
    for (; e + 8 <= nc; e += 8) {
        int4 q0 = sp4[(e >> 1) + 0], q1 = sp4[(e >> 1) + 1];
        int4 q2 = sp4[(e >> 1) + 2], q3 = sp4[(e >> 1) + 3];
        int s0 = q0.x & SMASK, s1 = q0.z & SMASK, s2 = q1.x & SMASK, s3 = q1.z & SMASK;
        int s4 = q2.x & SMASK, s5 = q2.z & SMASK, s6 = q3.x & SMASK, s7 = q3.z & SMASK;
        uint2 r0 = XW2[(size_t)s0 * 16 + l16];
        uint2 r1 = XW2[(size_t)s1 * 16 + l16];
        uint2 r2 = XW2[(size_t)s2 * 16 + l16];
        uint2 r3 = XW2[(size_t)s3 * 16 + l16];
        uint2 r4 = XW2[(size_t)s4 * 16 + l16];
        uint2 r5 = XW2[(size_t)s5 * 16 + l16];
        uint2 r6 = XW2[(size_t)s6 * 16 + l16];
        uint2 r7 = XW2[(size_t)s7 * 16 + l16];
        float c0 = __int_as_float(q0.y) * did, c1 = __int_as_float(q0.w) * did;
        float c2 = __int_as_float(q1.y) * did, c3 = __int_as_float(q1.w) * did;
        float c4 = __int_as_float(q2.y) * did, c5 = __int_as_float(q2.w) * did;
        float c6 = __int_as_float(q3.y) * did, c7 = __int_as_float(q3.w) * did;
        float2 v;
#define ACC1(R, C)                                                         \
        v = bup(R.x); a0 += (C) * v.x; a1 += (C) * v.y;                    \
        v = bup(R.y); a2 += (C) * v.x; a3 += (C) * v.y;
        ACC1(r0, c0) ACC1(r1, c1) ACC1(r2, c2) ACC1(r3, c3)
        ACC1(r4, c4) ACC1(r5, c5) ACC1(r6, c6) ACC1(r7, c7)
    }
    for (; e + 2 <= nc; e += 2) {
        int4 q = sp4[e >> 1];
        int s0 = q.x & SMASK, s1 = q.z & SMASK;
        uint2 r0 = XW2[(size_t)s0 * 16 + l16];
        uint2 r1 = XW2[(size_t)s1 * 16 + l16];
        float c0 = __int_as_float(q.y) * did, c1 = __int_as_float(q.w) * did;
        float2 v;
        ACC1(r0, c0) ACC1(r1, c1)
    }
    if (e < nc) {
        int2 p = sp[e];
        int s = p.x & SMASK;
        float c = __int_as_float(p.y) * did;
        uint2 r = XW2[(size_t)s * 16 + l16];
        float2 v;
        ACC1(r, c)
    }
#undef ACC1
    uint2 o;
    o.x = bpack(fmaxf(a0, 0.f), fmaxf(a1, 0.f));
    o.y = bpack(fmaxf(a2, 0.f), fmaxf(a3, 0.f));
    ((uint2*)Hb)[(size_t)d * 16 + l16] = o;
}

// ---------------- GEMM 2: HWs = bf16( dinv[row] * (Hbf16 @ W2) ) ----------------

__global__ void __launch_bounds__(256) gemm2_kernel(const unsigned int* __restrict__ Hb,
                                                    const float* __restrict__ W,
                                                    const float* __restrict__ dinv,
                                                    unsigned int* __restrict__ HWs,
                                                    int nRows) {
    __shared__ float HsT[64][128];   // 32 KB
    __shared__ float Ws[64][32];     // 8 KB
    int tid = threadIdx.x;
    {
        const float4* Wv = (const float4*)W;
        float4* Wsv = (float4*)&Ws[0][0];
        for (int i = tid; i < 512; i += 256) Wsv[i] = Wv[i];
    }
    int row0 = blockIdx.x * 128;
    int rmax = nRows - row0;
    for (int i = tid; i < 128 * 8; i += 256) {
        int r = i & 127, kq = i >> 7;  // conflict-free staging
        uint4 v = (r < rmax) ? ((const uint4*)(Hb + (size_t)(row0 + r) * 32))[kq]
                             : make_uint4(0u, 0u, 0u, 0u);
        float2 f;
        f = bup(v.x); HsT[8 * kq + 0][r] = f.x; HsT[8 * kq + 1][r] = f.y;
        f = bup(v.y); HsT[8 * kq + 2][r] = f.x; HsT[8 * kq + 3][r] = f.y;
        f = bup(v.z); HsT[8 * kq + 4][r] = f.x; HsT[8 * kq + 5][r] = f.y;
        f = bup(v.w); HsT[8 * kq + 6][r] = f.x; HsT[8 * kq + 7][r] = f.y;
    }
    __syncthreads();
    int tr = tid >> 3, tc = tid & 7;
    float acc[4][4] = {};
    float a[4], bb[4];
#pragma unroll 8
    for (int k = 0; k < 64; ++k) {
        *(float4*)a = *(const float4*)&HsT[k][4 * tr];
        *(float4*)bb = *(const float4*)&Ws[k][4 * tc];
#pragma unroll
        for (int i = 0; i < 4; ++i)
#pragma unroll
            for (int j = 0; j < 4; ++j) acc[i][j] += a[i] * bb[j];
    }
#pragma unroll
    for (int i = 0; i < 4; ++i) {
        int rl = 4 * tr + i;
        if (rl < rmax) {
            int row = row0 + rl;
            float di = dinv[row];
            uint2 o;
            o.x = bpack(acc[i][0] * di, acc[i][1] * di);
            o.y = bpack(acc[i][2] * di, acc[i][3] * di);
            ((uint2*)HWs)[(size_t)row * 8 + tc] = o;
        }
    }
}

// ---------------- agg layer 2: 8 nodes/wave, 4 ch/lane (uint2) -> d_out ----------------

__global__ void __launch_bounds__(256) agg2_kernel(const int2* __restrict__ rowRC,
                                                   const int2* __restrict__ seg2,
                                                   const unsigned int* __restrict__ HWs,
                                                   const float* __restrict__ dinv,
                                                   const float* __restrict__ b2,
                                                   float* __restrict__ out) {
    int l8 = threadIdx.x & 7;
    int d = blockIdx.x * 32 + (threadIdx.x >> 3);
    if (d >= N_NODES) return;
    const uint2* HW2 = (const uint2*)HWs;   // row = 8 uint2
    float did = dinv[d];
    float4 bv = ((const float4*)b2)[l8];
    uint2 sv = HW2[(size_t)d * 8 + l8];
    float2 f0 = bup(sv.x), f1 = bup(sv.y);
    float a0 = bv.x + did * f0.x, a1 = bv.y + did * f0.y;
    float a2 = bv.z + did * f1.x, a3 = bv.w + did * f1.y;
    int2 rc = rowRC[d];
    int nc = rc.y;
    const int2* sp = seg2 + rc.x;
    const int4* sp4 = (const int4*)sp;
    int e = 0;
    for (; e + 8 <= nc; e += 8) {
        int4 q0 = sp4[(e >> 1) + 0], q1 = sp4[(e >> 1) + 1];
        int4 q2 = sp4[(e >> 1) + 2], q3 = sp4[(e >> 1) + 3];
        int s0 = q0.x & SMASK, s1 = q0.z & SMASK, s2 = q1.x & SMASK, s3 = q1.z & SMASK;
        int s4 = q2.x & SMASK, s5 = q2.z & SMASK, s6 = q3.x & SMASK, s7 = q3.z & SMASK;
        uint2 r0 = HW2[(size_t)s0 * 8 + l8];
        uint2 r1 = HW2[(size_t)s1 * 8 + l8];
        uint2 r2 = HW2[(size_t)s2 * 8 + l8];
        uint2 r3 = HW2[(size_t)s3 * 8 + l8];
        uint2 r4 = HW2[(size_t)s4 * 8 + l8];
        uint2 r5 = HW2[(size_t)s5 * 8 + l8];
        uint2 r6 = HW2[(size_t)s6 * 8 + l8];
        uint2 r7 = HW2[(size_t)s7 * 8 + l8];
        float c0 = __int_as_float(q0.y) * did, c1 = __int_as_float(q0.w) * did;
        float c2 = __int_as_float(q1.y) * did, c3 = __int_as_float(q1.w) * did;
        float c4 = __int_as_float(q2.y) * did, c5 = __int_as_float(q2.w) * did;
        float c6 = __int_as_float(q3.y) * did, c7 = __int_as_float(q3.w) * did;
        float2 v;
#define ACC2(R, C)                                                         \
        v = bup(R.x); a0 += (C) * v.x; a1 += (C) * v.y;                    \
        v = bup(R.y); a2 += (C) * v.x; a3 += (C) * v.y;
        ACC2(r0, c0) ACC2(r1, c1) ACC2(r2, c2) ACC2(r3, c3)
        ACC2(r4, c4) ACC2(r5, c5) ACC2(r6, c6) ACC2(r7, c7)
    }
    for (; e + 2 <= nc; e += 2) {
        int4 q = sp4[e >> 1];
        int s0 = q.x & SMASK, s1 = q.z & SMASK;
        uint2 r0 = HW2[(size_t)s0 * 8 + l8];
        uint2 r1 = HW2[(size_t)s1 * 8 + l8];
        float c0 = __int_as_float(q.y) * did, c1 = __int_as_float(q.w) * did;
        float2 v;
        ACC2(r0, c0) ACC2(r1, c1)
    }
    if (e < nc) {
        int2 p = sp[e];
        int s = p.x & SMASK;
        float c = __int_as_float(p.y) * did;
        uint2 r = HW2[(size_t)s * 8 + l8];
        float2 v;
        ACC2(r, c)
    }
#undef ACC2
    ((float4*)out)[(size_t)d * 8 + l8] = make_float4(a0, a1, a2, a3);
}

// ---------------- launch ----------------

extern "C" void kernel_launch(void* const* d_in, const int* in_sizes, int n_in,
                              void* d_out, int out_size, void* d_ws, size_t ws_size,
                              hipStream_t stream) {
    const float* x = (const float*)d_in[0];
    const int* edge_index = (const int*)d_in[1];
    const float* ew = (const float*)d_in[2];
    const float* W1 = (const float*)d_in[3];
    const float* b1 = (const float*)d_in[4];
    const float* W2 = (const float*)d_in[5];
    const float* b2 = (const float*)d_in[6];
    float* out = (float*)d_out;

    const int* src = edge_index;
    const int* dst = edge_index + N_EDGES;

    char* ws = (char*)d_ws;
    size_t off = 0;
    auto carve = [&](size_t bytes) -> void* {
        void* p = ws + off;
        off += (bytes + 255) & ~(size_t)255;
        return p;
    };

    int* gcnt = (int*)carve(NB * 4);
    float* dinv = (float*)carve((size_t)N_NODES * 4);
    int2* rowRC = (int2*)carve((size_t)N_NODES * 8);
    int2* seg = (int2*)carve((size_t)NB * SEG_CAP * 8);         // 15.2 MB
    int2* seg2 = (int2*)carve((size_t)NB * SEG_CAP * 8);        // 15.2 MB
    unsigned int* XWs = (unsigned int*)carve((size_t)N_NODES * 32 * 4);  // 12.8 MB bf16x2
    unsigned int* Hb = (unsigned int*)carve((size_t)N_NODES * 32 * 4);   // 12.8 MB bf16x2
    unsigned int* HWs = XWs;  // alias: XWs dead after agg1

    hipMemsetAsync(gcnt, 0, NB * 4, stream);
    fused1_kernel<<<BIN_BLOCKS + G1_BLOCKS, 256, 0, stream>>>(src, dst, ew, gcnt, seg,
                                                              x, W1, XWs);
    bsort_kernel<<<NB, 256, 0, stream>>>(gcnt, seg, seg2, dinv, rowRC, XWs);
    agg1_kernel<<<(N_NODES + 15) / 16, 256, 0, stream>>>(rowRC, seg2, XWs, dinv, b1, Hb);
    gemm2_kernel<<<(N_NODES + 127) / 128, 256, 0, stream>>>(Hb, W2, dinv, HWs, N_NODES);
    agg2_kernel<<<(N_NODES + 31) / 32, 256, 0, stream>>>(rowRC, seg2, HWs, dinv, b2, out);
}

// Round 12
// 217.009 us; speedup vs baseline: 1.0971x; 1.0971x over previous
//
#include <hip/hip_runtime.h>

#define N_NODES 100000
#define N_EDGES 1600000
#define IN_C 64
#define HID_C 64
#define OUT_C 32

#define NB 391              // ceil(100000/256) dst buckets of 256 nodes
#define BSHIFT 8
#define BMASK 255
#define SEG_CAP 4864        // per-bucket capacity: mean 4096 + align pad + slack
#define EPB 4096            // edges per bin block (R10 value: long scatter runs win)
#define BIN_BLOCKS ((N_EDGES + EPB - 1) / EPB)  // 391
#define G1_BLOCKS ((N_NODES + 63) / 64)         // 1563
#define SMASK 0x1FFFF       // 17-bit src field
#define FIXSCALE 34359738368.0f   // 2^35: count<<48 | sum(w)<<35 can't overflow

// bf16 pack/unpack (round-to-nearest-even)
__device__ __forceinline__ unsigned int bpack(float a, float b) {
    unsigned int ua = __float_as_uint(a);
    ua += 0x7FFFu + ((ua >> 16) & 1u);
    unsigned int ub = __float_as_uint(b);
    ub += 0x7FFFu + ((ub >> 16) & 1u);
    return (ua >> 16) | (ub & 0xFFFF0000u);
}
__device__ __forceinline__ float2 bup(unsigned int v) {
    return make_float2(__uint_as_float(v << 16), __uint_as_float(v & 0xFFFF0000u));
}

// ---------------- fused pass 1: bin (blocks 0..390) + gemm1 unscaled (rest) ----------------
// Bin no longer stages records in LDS: flush re-reads src/dst/w (L2-hot) and
// recomputes the record. meta[] holds rank only. BinSh = 19 KB -> union 32 KB
// -> 5 blocks/CU (R10 was 51.5 KB -> 3 blocks/CU) with the SAME run length.

struct BinSh {
    int meta[EPB];      // 16 KB: rank within (block,bucket)
    int hist[NB];       // 1.6 KB
    int gbase[NB];      // 1.6 KB
};
struct G1Sh {
    float XsT[64][64];  // 16 KB
    float Ws[64][64];   // 16 KB
};
union FusedSh { BinSh b; G1Sh g; };  // 32 KB

__global__ void __launch_bounds__(256) fused1_kernel(
    const int* __restrict__ src, const int* __restrict__ dst,
    const float* __restrict__ w, int* __restrict__ gcnt, int2* __restrict__ seg,
    const float* __restrict__ X, const float* __restrict__ W,
    unsigned int* __restrict__ XWu) {
    __shared__ FusedSh sh;
    int tid = threadIdx.x;
    if (blockIdx.x < BIN_BLOCKS) {
        // ---- bin body ----
        for (int i = tid; i < NB; i += 256) sh.b.hist[i] = 0;
        __syncthreads();
        int e0 = blockIdx.x * EPB;
        int n = min(EPB, N_EDGES - e0);   // multiple of 4 (last block = 2560)
        const int4* dst4 = (const int4*)(dst + e0);
        int n4 = n >> 2;
        // phase 1: count + rank.  meta slot transposed (K*n4+i): stride-1 per lane.
        for (int i = tid; i < n4; i += 256) {
            int4 d = dst4[i];
            int b0 = d.x >> BSHIFT, b1 = d.y >> BSHIFT;
            int b2 = d.z >> BSHIFT, b3 = d.w >> BSHIFT;
            sh.b.meta[0 * n4 + i] = atomicAdd(&sh.b.hist[b0], 1);
            sh.b.meta[1 * n4 + i] = atomicAdd(&sh.b.hist[b1], 1);
            sh.b.meta[2 * n4 + i] = atomicAdd(&sh.b.hist[b2], 1);
            sh.b.meta[3 * n4 + i] = atomicAdd(&sh.b.hist[b3], 1);
        }
        __syncthreads();
        for (int b = tid; b < NB; b += 256) {
            int c = sh.b.hist[b];
            sh.b.gbase[b] = c ? atomicAdd(&gcnt[b], c) : 0;
        }
        __syncthreads();
        // phase 2: re-read edges (L2-hot), recompute record, scatter in runs.
        const int4* src4 = (const int4*)(src + e0);
        const float4* w4 = (const float4*)(w + e0);
        for (int i = tid; i < n4; i += 256) {
            int4 s = src4[i];
            int4 d = dst4[i];
            float4 ww = w4[i];
#define FL_ONE(K, SS, DD, WW)                                              \
            {                                                              \
                int b = (DD) >> BSHIFT;                                    \
                int pos = sh.b.gbase[b] + sh.b.meta[K * n4 + i];           \
                if (pos < SEG_CAP)                                         \
                    seg[(size_t)b * SEG_CAP + pos] =                       \
                        make_int2((SS) | (((DD) & BMASK) << 17),           \
                                  __float_as_int(WW));                     \
            }
            FL_ONE(0, s.x, d.x, ww.x)
            FL_ONE(1, s.y, d.y, ww.y)
            FL_ONE(2, s.z, d.z, ww.z)
            FL_ONE(3, s.w, d.w, ww.w)
#undef FL_ONE
        }
    } else {
        // ---- gemm1 body: XWu = bf16(X @ W1), unscaled ----
        {
            const float4* Wv = (const float4*)W;
            float4* Wsv = (float4*)&sh.g.Ws[0][0];
            for (int i = tid; i < 1024; i += 256) Wsv[i] = Wv[i];
        }
        int row0 = (blockIdx.x - BIN_BLOCKS) * 64;
        int rmax = N_NODES - row0;
        for (int i = tid; i < 64 * 16; i += 256) {
            int r = i & 63, kq = i >> 6;  // consecutive lanes -> consecutive rows (conflict-free)
            float4 v = (r < rmax) ? ((const float4*)(X + (size_t)(row0 + r) * IN_C))[kq]
                                  : make_float4(0.f, 0.f, 0.f, 0.f);
            sh.g.XsT[4 * kq + 0][r] = v.x;
            sh.g.XsT[4 * kq + 1][r] = v.y;
            sh.g.XsT[4 * kq + 2][r] = v.z;
            sh.g.XsT[4 * kq + 3][r] = v.w;
        }
        __syncthreads();
        int tr = tid >> 4, tc = tid & 15;
        float acc[4][4] = {};
        float a[4], bb[4];
#pragma unroll 8
        for (int k = 0; k < 64; ++k) {
            *(float4*)a = *(const float4*)&sh.g.XsT[k][4 * tr];
            *(float4*)bb = *(const float4*)&sh.g.Ws[k][4 * tc];
#pragma unroll
            for (int i = 0; i < 4; ++i)
#pragma unroll
                for (int j = 0; j < 4; ++j) acc[i][j] += a[i] * bb[j];
        }
#pragma unroll
        for (int i = 0; i < 4; ++i) {
            int rl = 4 * tr + i;
            if (rl < rmax) {
                int row = row0 + rl;
                uint2 o;
                o.x = bpack(acc[i][0], acc[i][1]);
                o.y = bpack(acc[i][2], acc[i][3]);
                ((uint2*)XWu)[(size_t)row * 16 + tc] = o;
            }
        }
    }
}

// ---------------- pass 2: per-bucket counting sort -> runs + dinv + XW scale ----------------
// 1024 threads (4x wave parallelism; block count 391 < CU count so per-block
// parallelism is the occupancy lever). No recs staging: flush re-reads seg (L2-hot).

__global__ void __launch_bounds__(1024) bsort_kernel(const int* __restrict__ gcnt,
                                                     const int2* __restrict__ seg,
                                                     int2* __restrict__ seg2,
                                                     float* __restrict__ dinv,
                                                     int2* __restrict__ rowRC,
                                                     unsigned int* __restrict__ XWs) {
    __shared__ unsigned long long packed[256];   // 2 KB
    __shared__ int meta[SEG_CAP];                // 19 KB: dl | rank<<8
    __shared__ int sarr[256];
    __shared__ int ofs0[256];
    __shared__ float dinvsh[256];
    int tid = threadIdx.x, b = blockIdx.x;
    int n = min(gcnt[b], SEG_CAP);
    const int2* sp = seg + (size_t)b * SEG_CAP;
    if (tid < 256) packed[tid] = 0ULL;
    __syncthreads();
    for (int i = tid; i < n; i += 1024) {
        int2 r = sp[i];
        int dl = (r.x >> 17) & BMASK;
        unsigned long long fixw =
            (unsigned long long)(__int_as_float(r.y) * FIXSCALE);
        unsigned long long old = atomicAdd(&packed[dl], (1ULL << 48) | fixw);
        meta[i] = dl | ((int)(old >> 48) << 8);
    }
    __syncthreads();
    int myc = 0, padc = 0;
    if (tid < 256) {
        unsigned long long p = packed[tid];
        myc = (int)(p >> 48);
        float degw = (float)((double)(p & ((1ULL << 48) - 1)) * (1.0 / (double)FIXSCALE));
        float dv = rsqrtf(1.0f + degw);  // self-loop w=1
        dinvsh[tid] = dv;
        int node = (b << BSHIFT) + tid;
        if (node < N_NODES) dinv[node] = dv;
        padc = (myc + 1) & ~1;  // even-align runs for int4 loads
        sarr[tid] = padc;
    }
    __syncthreads();
    for (int off = 1; off < 256; off <<= 1) {
        int tmp = 0;
        if (tid < 256 && tid >= off) tmp = sarr[tid - off];
        __syncthreads();
        if (tid < 256) sarr[tid] += tmp;
        __syncthreads();
    }
    if (tid < 256) {
        int excl = sarr[tid] - padc;
        int node = (b << BSHIFT) + tid;
        if (node < N_NODES) rowRC[node] = make_int2(b * SEG_CAP + excl, myc);
        ofs0[tid] = excl;
    }
    __syncthreads();
    int2* op = seg2 + (size_t)b * SEG_CAP;
    for (int i = tid; i < n; i += 1024) {
        int2 r = sp[i];                       // re-read, L2-hot
        int m = meta[i];
        int dl = m & BMASK, rank = m >> 8;
        op[ofs0[dl] + rank] = r;
    }
    // ---- scale tail: XWs[row] *= dinv[row] (bf16 in place), coalesced uint4 ----
    int baseRow = b << BSHIFT;
    int rowsHere = min(256, N_NODES - baseRow);
    uint4* XW4 = (uint4*)XWs;
    for (int i = tid; i < rowsHere * 8; i += 1024) {
        int nl = i >> 3;
        float s = dinvsh[nl];
        uint4 v = XW4[(size_t)(baseRow + nl) * 8 + (i & 7)];
        float2 f;
        f = bup(v.x); v.x = bpack(f.x * s, f.y * s);
        f = bup(v.y); v.y = bpack(f.x * s, f.y * s);
        f = bup(v.z); v.z = bpack(f.x * s, f.y * s);
        f = bup(v.w); v.w = bpack(f.x * s, f.y * s);
        XW4[(size_t)(baseRow + nl) * 8 + (i & 7)] = v;
    }
}

// ---------------- agg layer 1: 4 nodes/wave, 4 ch/lane (uint2), ReLU, bf16 out ----------

__global__ void __launch_bounds__(256) agg1_kernel(const int2* __restrict__ rowRC,
                                                   const int2* __restrict__ seg2,
                                                   const unsigned int* __restrict__ XWs,
                                                   const float* __restrict__ dinv,
                                                   const float* __restrict__ b1,
                                                   unsigned int* __restrict__ Hb) {
    int l16 = threadIdx.x & 15;
    int d = blockIdx.x * 16 + (threadIdx.x >> 4);
    if (d >= N_NODES) return;
    const uint2* XW2 = (const uint2*)XWs;   // row = 16 uint2
    float did = dinv[d];
    float4 bv = ((const float4*)b1)[l16];
    uint2 sv = XW2[(size_t)d * 16 + l16];
    float2 f0 = bup(sv.x), f1 = bup(sv.y);
    float a0 = bv.x + did * f0.x, a1 = bv.y + did * f0.y;
    float a2 = bv.z + did * f1.x, a3 = bv.w + did * f1.y;
    int2 rc = rowRC[d];
    int nc = rc.y;
    const int2* sp = seg2 + rc.x;
    const int4* sp4 = (const int4*)sp;
    int e = 0;
    for (; e + 8 <= nc; e += 8) {
        int4 q0 = sp4[(e >> 1) + 0], q1 = sp4[(e >> 1) + 1];
        int4 q2 = sp4[(e >> 1) + 2], q3 = sp4[(e >> 1) + 3];
        int s0 = q0.x & SMASK, s1 = q0.z & SMASK, s2 = q1.x & SMASK, s3 = q1.z & SMASK;
        int s4 = q2.x & SMASK, s5 = q2.z & SMASK, s6 = q3.x & SMASK, s7 = q3.z & SMASK;
        uint2 r0 = XW2[(size_t)s0 * 16 + l16];
        uint2 r1 = XW2[(size_t)s1 * 16 + l16];
        uint2 r2 = XW2[(size_t)s2 * 16 + l16];
        uint2 r3 = XW2[(size_t)s3 * 16 + l16];
        uint2 r4 = XW2[(size_t)s4 * 16 + l16];
        uint2 r5 = XW2[(size_t)s5 * 16 + l16];
        uint2 r6 = XW2[(size_t)s6 * 16 + l16];
        uint2 r7 = XW2[(size_t)s7 * 16 + l16];
        float c0 = __int_as_float(q0.y) * did, c1 = __int_as_float(q0.w) * did;
        float c2 = __int_as_float(q1.y) * did, c3 = __int_as_float(q1.w) * did;
        float c4 = __int_as_float(q2.y) * did, c5 = __int_as_float(q2.w) * did;
        float c6 = __int_as_float(q3.y) * did, c7 = __int_as_float(q3.w) * did;
        float2 v;
#define ACC1(R, C)                                                         \
        v = bup(R.x); a0 += (C) * v.x; a1 += (C) * v.y;                    \
        v = bup(R.y); a2 += (C) * v.x; a3 += (C) * v.y;
        ACC1(r0, c0) ACC1(r1, c1) ACC1(r2, c2) ACC1(r3, c3)
        ACC1(r4, c4) ACC1(r5, c5) ACC1(r6, c6) ACC1(r7, c7)
    }
    for (; e + 2 <= nc; e += 2) {
        int4 q = sp4[e >> 1];
        int s0 = q.x & SMASK, s1 = q.z & SMASK;
        uint2 r0 = XW2[(size_t)s0 * 16 + l16];
        uint2 r1 = XW2[(size_t)s1 * 16 + l16];
        float c0 = __int_as_float(q.y) * did, c1 = __int_as_float(q.w) * did;
        float2 v;
        ACC1(r0, c0) ACC1(r1, c1)
    }
    if (e < nc) {
        int2 p = sp[e];
        int s = p.x & SMASK;
        float c = __int_as_float(p.y) * did;
        uint2 r = XW2[(size_t)s * 16 + l16];
        float2 v;
        ACC1(r, c)
    }
#undef ACC1
    uint2 o;
    o.x = bpack(fmaxf(a0, 0.f), fmaxf(a1, 0.f));
    o.y = bpack(fmaxf(a2, 0.f), fmaxf(a3, 0.f));
    ((uint2*)Hb)[(size_t)d * 16 + l16] = o;
}

// ---------------- GEMM 2: HWs = bf16( dinv[row] * (Hbf16 @ W2) ) ----------------

__global__ void __launch_bounds__(256) gemm2_kernel(const unsigned int* __restrict__ Hb,
                                                    const float* __restrict__ W,
                                                    const float* __restrict__ dinv,
                                                    unsigned int* __restrict__ HWs,
                                                    int nRows) {
    __shared__ float HsT[64][128];   // 32 KB
    __shared__ float Ws[64][32];     // 8 KB
    int tid = threadIdx.x;
    {
        const float4* Wv = (const float4*)W;
        float4* Wsv = (float4*)&Ws[0][0];
        for (int i = tid; i < 512; i += 256) Wsv[i] = Wv[i];
    }
    int row0 = blockIdx.x * 128;
    int rmax = nRows - row0;
    for (int i = tid; i < 128 * 8; i += 256) {
        int r = i & 127, kq = i >> 7;  // conflict-free staging
        uint4 v = (r < rmax) ? ((const uint4*)(Hb + (size_t)(row0 + r) * 32))[kq]
                             : make_uint4(0u, 0u, 0u, 0u);
        float2 f;
        f = bup(v.x); HsT[8 * kq + 0][r] = f.x; HsT[8 * kq + 1][r] = f.y;
        f = bup(v.y); HsT[8 * kq + 2][r] = f.x; HsT[8 * kq + 3][r] = f.y;
        f = bup(v.z); HsT[8 * kq + 4][r] = f.x; HsT[8 * kq + 5][r] = f.y;
        f = bup(v.w); HsT[8 * kq + 6][r] = f.x; HsT[8 * kq + 7][r] = f.y;
    }
    __syncthreads();
    int tr = tid >> 3, tc = tid & 7;
    float acc[4][4] = {};
    float a[4], bb[4];
#pragma unroll 8
    for (int k = 0; k < 64; ++k) {
        *(float4*)a = *(const float4*)&HsT[k][4 * tr];
        *(float4*)bb = *(const float4*)&Ws[k][4 * tc];
#pragma unroll
        for (int i = 0; i < 4; ++i)
#pragma unroll
            for (int j = 0; j < 4; ++j) acc[i][j] += a[i] * bb[j];
    }
#pragma unroll
    for (int i = 0; i < 4; ++i) {
        int rl = 4 * tr + i;
        if (rl < rmax) {
            int row = row0 + rl;
            float di = dinv[row];
            uint2 o;
            o.x = bpack(acc[i][0] * di, acc[i][1] * di);
            o.y = bpack(acc[i][2] * di, acc[i][3] * di);
            ((uint2*)HWs)[(size_t)row * 8 + tc] = o;
        }
    }
}

// ---------------- agg layer 2: 8 nodes/wave, 4 ch/lane (uint2) -> d_out ----------------

__global__ void __launch_bounds__(256) agg2_kernel(const int2* __restrict__ rowRC,
                                                   const int2* __restrict__ seg2,
                                                   const unsigned int* __restrict__ HWs,
                                                   const float* __restrict__ dinv,
                                                   const float* __restrict__ b2,
                                                   float* __restrict__ out) {
    int l8 = threadIdx.x & 7;
    int d = blockIdx.x * 32 + (threadIdx.x >> 3);
    if (d >= N_NODES) return;
    const uint2* HW2 = (const uint2*)HWs;   // row = 8 uint2
    float did = dinv[d];
    float4 bv = ((const float4*)b2)[l8];
    uint2 sv = HW2[(size_t)d * 8 + l8];
    float2 f0 = bup(sv.x), f1 = bup(sv.y);
    float a0 = bv.x + did * f0.x, a1 = bv.y + did * f0.y;
    float a2 = bv.z + did * f1.x, a3 = bv.w + did * f1.y;
    int2 rc = rowRC[d];
    int nc = rc.y;
    const int2* sp = seg2 + rc.x;
    const int4* sp4 = (const int4*)sp;
    int e = 0;
    for (; e + 8 <= nc; e += 8) {
        int4 q0 = sp4[(e >> 1) + 0], q1 = sp4[(e >> 1) + 1];
        int4 q2 = sp4[(e >> 1) + 2], q3 = sp4[(e >> 1) + 3];
        int s0 = q0.x & SMASK, s1 = q0.z & SMASK, s2 = q1.x & SMASK, s3 = q1.z & SMASK;
        int s4 = q2.x & SMASK, s5 = q2.z & SMASK, s6 = q3.x & SMASK, s7 = q3.z & SMASK;
        uint2 r0 = HW2[(size_t)s0 * 8 + l8];
        uint2 r1 = HW2[(size_t)s1 * 8 + l8];
        uint2 r2 = HW2[(size_t)s2 * 8 + l8];
        uint2 r3 = HW2[(size_t)s3 * 8 + l8];
        uint2 r4 = HW2[(size_t)s4 * 8 + l8];
        uint2 r5 = HW2[(size_t)s5 * 8 + l8];
        uint2 r6 = HW2[(size_t)s6 * 8 + l8];
        uint2 r7 = HW2[(size_t)s7 * 8 + l8];
        float c0 = __int_as_float(q0.y) * did, c1 = __int_as_float(q0.w) * did;
        float c2 = __int_as_float(q1.y) * did, c3 = __int_as_float(q1.w) * did;
        float c4 = __int_as_float(q2.y) * did, c5 = __int_as_float(q2.w) * did;
        float c6 = __int_as_float(q3.y) * did, c7 = __int_as_float(q3.w) * did;
        float2 v;
#define ACC2(R, C)                                                         \
        v = bup(R.x); a0 += (C) * v.x; a1 += (C) * v.y;                    \
        v = bup(R.y); a2 += (C) * v.x; a3 += (C) * v.y;
        ACC2(r0, c0) ACC2(r1, c1) ACC2(r2, c2) ACC2(r3, c3)
        ACC2(r4, c4) ACC2(r5, c5) ACC2(r6, c6) ACC2(r7, c7)
    }
    for (; e + 2 <= nc; e += 2) {
        int4 q = sp4[e >> 1];
        int s0 = q.x & SMASK, s1 = q.z & SMASK;
        uint2 r0 = HW2[(size_t)s0 * 8 + l8];
        uint2 r1 = HW2[(size_t)s1 * 8 + l8];
        float c0 = __int_as_float(q.y) * did, c1 = __int_as_float(q.w) * did;
        float2 v;
        ACC2(r0, c0) ACC2(r1, c1)
    }
    if (e < nc) {
        int2 p = sp[e];
        int s = p.x & SMASK;
        float c = __int_as_float(p.y) * did;
        uint2 r = HW2[(size_t)s * 8 + l8];
        float2 v;
        ACC2(r, c)
    }
#undef ACC2
    ((float4*)out)[(size_t)d * 8 + l8] = make_float4(a0, a1, a2, a3);
}

// ---------------- launch ----------------

extern "C" void kernel_launch(void* const* d_in, const int* in_sizes, int n_in,
                              void* d_out, int out_size, void* d_ws, size_t ws_size,
                              hipStream_t stream) {
    const float* x = (const float*)d_in[0];
    const int* edge_index = (const int*)d_in[1];
    const float* ew = (const float*)d_in[2];
    const float* W1 = (const float*)d_in[3];
    const float* b1 = (const float*)d_in[4];
    const float* W2 = (const float*)d_in[5];
    const float* b2 = (const float*)d_in[6];
    float* out = (float*)d_out;

    const int* src = edge_index;
    const int* dst = edge_index + N_EDGES;

    char* ws = (char*)d_ws;
    size_t off = 0;
    auto carve = [&](size_t bytes) -> void* {
        void* p = ws + off;
        off += (bytes + 255) & ~(size_t)255;
        return p;
    };

    int* gcnt = (int*)carve(NB * 4);
    float* dinv = (float*)carve((size_t)N_NODES * 4);
    int2* rowRC = (int2*)carve((size_t)N_NODES * 8);
    int2* seg = (int2*)carve((size_t)NB * SEG_CAP * 8);         // 15.2 MB
    int2* seg2 = (int2*)carve((size_t)NB * SEG_CAP * 8);        // 15.2 MB
    unsigned int* XWs = (unsigned int*)carve((size_t)N_NODES * 32 * 4);  // 12.8 MB bf16x2
    unsigned int* Hb = (unsigned int*)carve((size_t)N_NODES * 32 * 4);   // 12.8 MB bf16x2
    unsigned int* HWs = XWs;  // alias: XWs dead after agg1

    hipMemsetAsync(gcnt, 0, NB * 4, stream);
    fused1_kernel<<<BIN_BLOCKS + G1_BLOCKS, 256, 0, stream>>>(src, dst, ew, gcnt, seg,
                                                              x, W1, XWs);
    bsort_kernel<<<NB, 1024, 0, stream>>>(gcnt, seg, seg2, dinv, rowRC, XWs);
    agg1_kernel<<<(N_NODES + 15) / 16, 256, 0, stream>>>(rowRC, seg2, XWs, dinv, b1, Hb);
    gemm2_kernel<<<(N_NODES + 127) / 128, 256, 0, stream>>>(Hb, W2, dinv, HWs, N_NODES);
    agg2_kernel<<<(N_NODES + 31) / 32, 256, 0, stream>>>(rowRC, seg2, HWs, dinv, b2, out);
}